// Round 8
// baseline (494.209 us; speedup 1.0000x reference)
//
#include <hip/hip_runtime.h>
#include <math.h>

// TinyMoE: B=8192 tokens, H=1024, E=8 experts, top_k=2.
// Sparse top-2 MoE. Split-fp16 2-pass MFMA GEMMs (A = hi+lo fp16, B = fp16).
// Round 5 kernel, fourth submission (r5/r7: GPU acquisition timeouts; r6:
// container failed twice — infra; kernel re-audited for hang/OOB/LDS/swizzle).
// 256x256/BK=32 tiles (2x arithmetic intensity), double-buffered
// one-barrier-per-step prefetch, XCD panel swizzle (expert-per-XCD, B-panel
// L2-resident), setprio around MFMA; OUTC + separate combine kernel.
// Outputs: combined [B,H] fp32 at d_out[0], weights [B,E] fp32 at d_out[B*H].

#define HB 1024
#define NB 8192
#define NE 8
#define RTOK 16   // tokens per router block

#define BM 256
#define BN 256
#define BK 32

typedef unsigned short ushort_t;
typedef unsigned int u32;
typedef _Float16 f16;
typedef __attribute__((ext_vector_type(8))) _Float16 hfx8;
typedef __attribute__((ext_vector_type(4))) float f32x4;

__device__ __forceinline__ float gelu_exact(float x) {
  return 0.5f * x * (1.0f + erff(x * 0.70710678118654752440f));
}
// global -> LDS direct copy, 16B per lane, 1KB per wave-call. LDS dest is
// wave-uniform base + lane*16 (linear); swizzle is baked into the per-lane
// GLOBAL source address (rule 21: same involution at stage-source and read).
__device__ __forceinline__ void gload16(const void* g, void* l) {
  __builtin_amdgcn_global_load_lds((const __attribute__((address_space(1))) u32*)g,
                                   (__attribute__((address_space(3))) u32*)l, 16, 0, 0);
}

// ---------------- zero counts (padded: cnt[e*16]) ----------------
__global__ void zero_cnt_kernel(int* cnt) {
  if (threadIdx.x < NE * 16) cnt[threadIdx.x] = 0;
}

// ---------------- X fp32 -> fp16 hi/lo split ----------------
__global__ __launch_bounds__(256) void xsplit_kernel(
    const float* __restrict__ X, f16* __restrict__ Xh, f16* __restrict__ Xl)
{
  const size_t i = ((size_t)blockIdx.x * 256 + threadIdx.x) * 8;
  float4 a = *(const float4*)(X + i);
  float4 b = *(const float4*)(X + i + 4);
  float f[8] = {a.x, a.y, a.z, a.w, b.x, b.y, b.z, b.w};
  hfx8 h, l;
  #pragma unroll
  for (int q = 0; q < 8; ++q) {
    f16 hh = (f16)f[q];
    h[q] = hh;
    l[q] = (f16)(f[q] - (float)hh);
  }
  *(hfx8*)(Xh + i) = h;
  *(hfx8*)(Xl + i) = l;
}

// ---------------- W transpose -> fp16 (hi only) ----------------
// W[e][k][n] fp32  ->  T[e][n][k] fp16 (B-fragments read contiguous K).
__global__ __launch_bounds__(256) void wsplit_kernel(
    const float* __restrict__ W1, const float* __restrict__ W2,
    f16* __restrict__ T1h, f16* __restrict__ T2h)
{
  __shared__ float sT[32][33];
  const int e = blockIdx.z >> 1;
  const int which = blockIdx.z & 1;
  const float* W = (which ? W2 : W1) + ((size_t)e << 20);
  f16* Th = (which ? T2h : T1h) + ((size_t)e << 20);
  const int k0 = blockIdx.x << 5;
  const int n0 = blockIdx.y << 5;
  const int r = threadIdx.x >> 3;   // 0..31
  const int q = threadIdx.x & 7;    // 0..7
  float4 v = *(const float4*)(W + (size_t)(k0 + r) * HB + n0 + q * 4);
  sT[r][q*4+0] = v.x; sT[r][q*4+1] = v.y; sT[r][q*4+2] = v.z; sT[r][q*4+3] = v.w;
  __syncthreads();
  f16 hv[4];
  #pragma unroll
  for (int j = 0; j < 4; ++j) hv[j] = (f16)sT[q*4+j][r];   // = W[k0+q*4+j][n0+r]
  const size_t off = (size_t)(n0 + r) * HB + k0 + q * 4;
  *(ushort4*)(Th + off) = *(ushort4*)hv;
}

// ---------------- router: softmax + top2, hierarchical counting ----------------
__global__ __launch_bounds__(256) void router_kernel(
    const float* __restrict__ X, const float* __restrict__ Wr, const float* __restrict__ br,
    float* __restrict__ wout, int* __restrict__ cnt,
    int* __restrict__ list, float* __restrict__ wlist)
{
  __shared__ int   sCnt[NE];
  __shared__ int   sBase[NE];
  __shared__ int   sE[RTOK][2];
  __shared__ int   sOff[RTOK][2];
  __shared__ float sW[RTOK][2];

  const int tid = threadIdx.x;
  if (tid < NE) sCnt[tid] = 0;
  __syncthreads();

  const int wv = tid >> 6;
  const int lane = tid & 63;

  for (int i = 0; i < 4; ++i) {
    const int s = wv * 4 + i;
    const int t = blockIdx.x * RTOK + s;
    const float* xr = X + (size_t)t * HB;
    float p0=0,p1=0,p2=0,p3=0,p4=0,p5=0,p6=0,p7=0;
    for (int h0 = 0; h0 < HB; h0 += 64) {
      float xv = xr[h0 + lane];
      const float4 wa = *(const float4*)(Wr + (size_t)(h0 + lane) * NE);
      const float4 wb = *(const float4*)(Wr + (size_t)(h0 + lane) * NE + 4);
      p0 += xv * wa.x; p1 += xv * wa.y; p2 += xv * wa.z; p3 += xv * wa.w;
      p4 += xv * wb.x; p5 += xv * wb.y; p6 += xv * wb.z; p7 += xv * wb.w;
    }
    #pragma unroll
    for (int off = 1; off < 64; off <<= 1) {
      p0 += __shfl_xor(p0, off); p1 += __shfl_xor(p1, off);
      p2 += __shfl_xor(p2, off); p3 += __shfl_xor(p3, off);
      p4 += __shfl_xor(p4, off); p5 += __shfl_xor(p5, off);
      p6 += __shfl_xor(p6, off); p7 += __shfl_xor(p7, off);
    }
    if (lane == 0) {
      float w[8];
      w[0]=p0+br[0]; w[1]=p1+br[1]; w[2]=p2+br[2]; w[3]=p3+br[3];
      w[4]=p4+br[4]; w[5]=p5+br[5]; w[6]=p6+br[6]; w[7]=p7+br[7];
      float m = w[0];
      #pragma unroll
      for (int e = 1; e < 8; ++e) m = fmaxf(m, w[e]);
      float sm = 0.f;
      #pragma unroll
      for (int e = 0; e < 8; ++e) { w[e] = expf(w[e] - m); sm += w[e]; }
      const float inv = 1.f / sm;
      #pragma unroll
      for (int e = 0; e < 8; ++e) w[e] *= inv;
      float4 w03; w03.x=w[0]; w03.y=w[1]; w03.z=w[2]; w03.w=w[3];
      float4 w47; w47.x=w[4]; w47.y=w[5]; w47.z=w[6]; w47.w=w[7];
      *(float4*)(wout + (size_t)t * NE)     = w03;
      *(float4*)(wout + (size_t)t * NE + 4) = w47;
      int i0 = 0; float v0 = w[0];
      #pragma unroll
      for (int e = 1; e < 8; ++e) if (w[e] > v0) { v0 = w[e]; i0 = e; }
      int i1 = -1; float v1 = -1.f;
      #pragma unroll
      for (int e = 0; e < 8; ++e) if (e != i0 && w[e] > v1) { v1 = w[e]; i1 = e; }
      const float rn = 1.f / (v0 + v1 + 1e-9f);
      const int o0 = atomicAdd(&sCnt[i0], 1);
      const int o1 = atomicAdd(&sCnt[i1], 1);
      sE[s][0] = i0; sOff[s][0] = o0; sW[s][0] = v0 * rn;
      sE[s][1] = i1; sOff[s][1] = o1; sW[s][1] = v1 * rn;
    }
  }
  __syncthreads();
  if (tid < NE) sBase[tid] = atomicAdd(&cnt[tid * 16], sCnt[tid]);
  __syncthreads();
  if (tid < RTOK * 2) {
    const int s = tid >> 1, j = tid & 1;
    const int t = blockIdx.x * RTOK + s;
    const int e = sE[s][j];
    const int pos = sBase[e] + sOff[s][j];
    list[e * NB + pos]  = t * 2 + j;
    wlist[e * NB + pos] = sW[s][j];
  }
}

// Per-step stage: 6 x gload16 per thread fills A-hi/A-lo/B [256][32] tiles.
#define STG(bf, k) do { \
    gload16(pAh0 + (k), &sA[bf][0][w16][0]); \
    gload16(pAh1 + (k), &sA[bf][0][128 + w16][0]); \
    gload16(pAl0 + (k), &sA[bf][1][w16][0]); \
    gload16(pAl1 + (k), &sA[bf][1][128 + w16][0]); \
    gload16(pB0  + (k), &sB[bf][w16][0]); \
    gload16(pB1  + (k), &sB[bf][128 + w16][0]); \
  } while (0)

#define MFMA_STEP(cur) do { \
    hfx8 bfr[4]; \
    _Pragma("unroll") \
    for (int n = 0; n < 4; ++n) bfr[n] = *(const hfx8*)&sB[cur][wc * 64 + n * 16 + lrow][col]; \
    __builtin_amdgcn_s_setprio(1); \
    _Pragma("unroll") \
    for (int m = 0; m < 8; ++m) { \
      const hfx8 ah = *(const hfx8*)&sA[cur][0][wr * 128 + m * 16 + lrow][col]; \
      const hfx8 al = *(const hfx8*)&sA[cur][1][wr * 128 + m * 16 + lrow][col]; \
      _Pragma("unroll") \
      for (int n = 0; n < 4; ++n) { \
        acc[m][n] = __builtin_amdgcn_mfma_f32_16x16x32_f16(ah, bfr[n], acc[m][n], 0, 0, 0); \
        acc[m][n] = __builtin_amdgcn_mfma_f32_16x16x32_f16(al, bfr[n], acc[m][n], 0, 0, 0); \
      } \
    } \
    __builtin_amdgcn_s_setprio(0); \
  } while (0)

// ---------------- GEMM1: H1 = gelu(X @ W1 + b1), split-fp16 2-pass ----------------
__global__ __launch_bounds__(512, 2) void gemm1_kernel(
    const f16* __restrict__ Xh, const f16* __restrict__ Xl,
    const f16* __restrict__ Wh,
    const float* __restrict__ b1, const int* __restrict__ cnt, const int* __restrict__ list,
    f16* __restrict__ H1h, f16* __restrict__ H1l)
{
  // XCD panel swizzle: expert = b&7 (one expert per XCD), n-panel = b>>8, m = (b>>3)&31.
  const int b  = blockIdx.x + (blockIdx.y << 5) + (blockIdx.z << 7);
  const int ve = b & 7;
  const int vn = (b >> 8) & 3;
  const int vm = (b >> 3) & 31;
  const int ne = cnt[ve << 4];
  const int m0 = vm * BM;
  if (m0 >= ne) return;
  const int n0 = vn * BN;

  __shared__ f16 sA[2][2][BM][BK];   // [buf][hi/lo][row][k]
  __shared__ f16 sB[2][BN][BK];
  __shared__ int sId[BM];

  const int tid = threadIdx.x;
  if (tid < BM) {
    int idx = m0 + tid;
    sId[tid] = (idx < ne) ? list[ve * NB + idx] : -1;
  }
  __syncthreads();

  // staging source pointers (slot XOR-swizzled: phys p holds logical p^((row>>1)&3))
  const int lr = tid >> 2;                              // 0..127
  const int sl = (((tid & 3) ^ ((lr >> 1) & 3)) << 3);  // f16 elements
  const int rid0 = sId[lr], rid1 = sId[128 + lr];
  const f16* pAh0 = Xh + ((size_t)(rid0 < 0 ? 0 : (rid0 >> 1)) << 10) + sl;
  const f16* pAh1 = Xh + ((size_t)(rid1 < 0 ? 0 : (rid1 >> 1)) << 10) + sl;
  const f16* pAl0 = Xl + ((size_t)(rid0 < 0 ? 0 : (rid0 >> 1)) << 10) + sl;
  const f16* pAl1 = Xl + ((size_t)(rid1 < 0 ? 0 : (rid1 >> 1)) << 10) + sl;
  const f16* pB0  = Wh + ((size_t)ve << 20) + ((size_t)(n0 + lr) << 10) + sl;
  const f16* pB1  = Wh + ((size_t)ve << 20) + ((size_t)(n0 + 128 + lr) << 10) + sl;
  const int w16 = (tid >> 6) << 4;                      // wave's 16-row chunk

  // read-side fragment addressing
  const int lane = tid & 63, wid = tid >> 6;
  const int wr = wid >> 2, wc = wid & 3;                // 2M x 4N waves
  const int lrow = lane & 15, sgrp = lane >> 4;
  const int col = ((sgrp ^ ((lrow >> 1) & 3)) << 3);

  f32x4 acc[8][4];
  #pragma unroll
  for (int i = 0; i < 8; ++i)
    #pragma unroll
    for (int j = 0; j < 4; ++j) acc[i][j] = (f32x4){0.f, 0.f, 0.f, 0.f};

  STG(0, 0);
  __syncthreads();
  int cur = 0;
  for (int t = 0; t < 31; ++t) {
    STG(cur ^ 1, (t + 1) * BK);
    MFMA_STEP(cur);
    __syncthreads();            // drains prefetch (vmcnt) + ds reads, one barrier/step
    cur ^= 1;
  }
  MFMA_STEP(cur);

  const int rgrp = (lane >> 4) << 2;
  #pragma unroll
  for (int m = 0; m < 8; ++m)
    #pragma unroll
    for (int r = 0; r < 4; ++r) {
      const int row = wr * 128 + m * 16 + rgrp + r;
      const int orid = sId[row];
      if (orid < 0) continue;
      #pragma unroll
      for (int n = 0; n < 4; ++n) {
        const int c = n0 + wc * 64 + n * 16 + lrow;
        float v = acc[m][n][r] + b1[ve * HB + c];
        v = gelu_exact(v);
        f16 h = (f16)v;
        H1h[(size_t)orid * HB + c] = h;
        H1l[(size_t)orid * HB + c] = (f16)(v - (float)h);
      }
    }
}

// ---------------- GEMM2: OUTC = w * (H1 @ W2 + b2), split-fp16 2-pass ----------------
__global__ __launch_bounds__(512, 2) void gemm2_kernel(
    const f16* __restrict__ H1h, const f16* __restrict__ H1l,
    const f16* __restrict__ Wh,
    const float* __restrict__ b2, const int* __restrict__ cnt, const int* __restrict__ list,
    const float* __restrict__ wlist, float* __restrict__ OUTC)
{
  const int b  = blockIdx.x + (blockIdx.y << 5) + (blockIdx.z << 7);
  const int ve = b & 7;
  const int vn = (b >> 8) & 3;
  const int vm = (b >> 3) & 31;
  const int ne = cnt[ve << 4];
  const int m0 = vm * BM;
  if (m0 >= ne) return;
  const int n0 = vn * BN;

  __shared__ f16 sA[2][2][BM][BK];
  __shared__ f16 sB[2][BN][BK];
  __shared__ int sId[BM];
  __shared__ float sWt[BM];

  const int tid = threadIdx.x;
  if (tid < BM) {
    int idx = m0 + tid;
    if (idx < ne) { sId[tid] = list[ve * NB + idx]; sWt[tid] = wlist[ve * NB + idx]; }
    else          { sId[tid] = -1;                  sWt[tid] = 0.f; }
  }
  __syncthreads();

  const int lr = tid >> 2;
  const int sl = (((tid & 3) ^ ((lr >> 1) & 3)) << 3);
  const int rid0 = sId[lr], rid1 = sId[128 + lr];
  const f16* pAh0 = H1h + ((size_t)(rid0 < 0 ? 0 : rid0) << 10) + sl;
  const f16* pAh1 = H1h + ((size_t)(rid1 < 0 ? 0 : rid1) << 10) + sl;
  const f16* pAl0 = H1l + ((size_t)(rid0 < 0 ? 0 : rid0) << 10) + sl;
  const f16* pAl1 = H1l + ((size_t)(rid1 < 0 ? 0 : rid1) << 10) + sl;
  const f16* pB0  = Wh + ((size_t)ve << 20) + ((size_t)(n0 + lr) << 10) + sl;
  const f16* pB1  = Wh + ((size_t)ve << 20) + ((size_t)(n0 + 128 + lr) << 10) + sl;
  const int w16 = (tid >> 6) << 4;

  const int lane = tid & 63, wid = tid >> 6;
  const int wr = wid >> 2, wc = wid & 3;
  const int lrow = lane & 15, sgrp = lane >> 4;
  const int col = ((sgrp ^ ((lrow >> 1) & 3)) << 3);

  f32x4 acc[8][4];
  #pragma unroll
  for (int i = 0; i < 8; ++i)
    #pragma unroll
    for (int j = 0; j < 4; ++j) acc[i][j] = (f32x4){0.f, 0.f, 0.f, 0.f};

  STG(0, 0);
  __syncthreads();
  int cur = 0;
  for (int t = 0; t < 31; ++t) {
    STG(cur ^ 1, (t + 1) * BK);
    MFMA_STEP(cur);
    __syncthreads();
    cur ^= 1;
  }
  MFMA_STEP(cur);

  const int rgrp = (lane >> 4) << 2;
  #pragma unroll
  for (int m = 0; m < 8; ++m)
    #pragma unroll
    for (int r = 0; r < 4; ++r) {
      const int row = wr * 128 + m * 16 + rgrp + r;
      const int orid = sId[row];
      if (orid < 0) continue;
      const float wrow = sWt[row];
      #pragma unroll
      for (int n = 0; n < 4; ++n) {
        const int c = n0 + wc * 64 + n * 16 + lrow;
        OUTC[(size_t)orid * HB + c] = (acc[m][n][r] + b2[ve * HB + c]) * wrow;
      }
    }
}

// ---------------- combine: out[t] = OUTC[t*2] + OUTC[t*2+1] ----------------
__global__ __launch_bounds__(256) void combine_kernel(
    const float* __restrict__ OUTC, float* __restrict__ out)
{
  const int i = blockIdx.x * 256 + threadIdx.x;   // float4 index over [NB][HB]
  const int t = i >> 8;                           // HB/4 = 256 float4 per row
  const int c4 = i & 255;
  const float4 a = *((const float4*)(OUTC + ((size_t)t << 11)) + c4);
  const float4 b = *((const float4*)(OUTC + ((size_t)t << 11) + HB) + c4);
  float4 o; o.x = a.x + b.x; o.y = a.y + b.y; o.z = a.z + b.z; o.w = a.w + b.w;
  *((float4*)out + i) = o;
}

extern "C" void kernel_launch(void* const* d_in, const int* in_sizes, int n_in,
                              void* d_out, int out_size, void* d_ws, size_t ws_size,
                              hipStream_t stream) {
  const float* X  = (const float*)d_in[0];
  const float* Wr = (const float*)d_in[1];
  const float* br = (const float*)d_in[2];
  const float* W1 = (const float*)d_in[3];
  const float* b1 = (const float*)d_in[4];
  const float* W2 = (const float*)d_in[5];
  const float* b2 = (const float*)d_in[6];
  float* out = (float*)d_out;

  char* ws = (char*)d_ws;
  size_t o = 0;
  int*   cnt   = (int*)(ws + o);   o += 512;                       // padded: cnt[e*16]
  int*   list  = (int*)(ws + o);   o += (size_t)NE * NB * 4;
  float* wlist = (float*)(ws + o); o += (size_t)NE * NB * 4;
  f16*   T1h   = (f16*)(ws + o);   o += (size_t)NE * HB * HB * 2;  // 16 MB
  f16*   T2h   = (f16*)(ws + o);   o += (size_t)NE * HB * HB * 2;  // 16 MB
  f16*   H1h   = (f16*)(ws + o);   o += (size_t)NB * 2 * HB * 2;   // 32 MB
  f16*   H1l   = (f16*)(ws + o);   o += (size_t)NB * 2 * HB * 2;   // 32 MB
  // Region shared in time: Xh/Xl live only through gemm1; OUTC written by gemm2.
  char*  region = ws + o;          o += (size_t)NB * 2 * HB * 4;   // 64 MB
  f16*   Xh = (f16*)region;                                        // 16 MB
  f16*   Xl = (f16*)(region + (size_t)NB * HB * 2);                // 16 MB
  float* OUTC = (float*)region;                                    // 64 MB (aliases Xh/Xl)

  zero_cnt_kernel<<<1, 128, 0, stream>>>(cnt);
  xsplit_kernel<<<NB * HB / (8 * 256), 256, 0, stream>>>(X, Xh, Xl);
  wsplit_kernel<<<dim3(HB / 32, HB / 32, NE * 2), 256, 0, stream>>>(W1, W2, T1h, T2h);
  router_kernel<<<NB / RTOK, 256, 0, stream>>>(X, Wr, br, out + (size_t)NB * HB, cnt, list, wlist);
  gemm1_kernel<<<dim3(NB / BM, HB / BN, NE), 512, 0, stream>>>(Xh, Xl, T1h, b1, cnt, list, H1h, H1l);
  gemm2_kernel<<<dim3(NB / BM, HB / BN, NE), 512, 0, stream>>>(H1h, H1l, T2h, b2, cnt, list, wlist, OUTC);
  combine_kernel<<<NB * HB / 1024, 256, 0, stream>>>(OUTC, out);
}